// Round 1
// baseline (170.281 us; speedup 1.0000x reference)
//
#include <hip/hip_runtime.h>
#include <stdint.h>

#define NB 32
#define NA 48
#define HIN 64
#define EIN 32
#define HH 64
#define HG 16
#define NCELLS 5

// workspace layout (in floats)
#define ESUM_SZ  (NB*NA*HG*HH)          // 1,572,864 floats (6.29 MB)
#define WIHT_OFF (ESUM_SZ)
#define WIHT_SZ  (HG*3*HH)              // 3072
#define WHHT_OFF (WIHT_OFF + WIHT_SZ)
#define WHHT_SZ  (HH*3*HH)              // 12288

// Kernel 0: transpose small GRU weight matrices for coalesced per-lane reads.
// W_ihT[g*192 + c] = W_ih[c*16 + g];  W_hhT[h*192 + c] = W_hh[c*64 + h]
__global__ void transpose_weights(const float* __restrict__ W_ih,
                                  const float* __restrict__ W_hh,
                                  float* __restrict__ ws) {
    int idx = blockIdx.x * blockDim.x + threadIdx.x;
    if (idx < WIHT_SZ) {
        int g = idx / (3 * HH);
        int c = idx % (3 * HH);
        ws[WIHT_OFF + idx] = W_ih[c * HG + g];
    }
    idx -= WIHT_SZ;
    if (idx >= 0 && idx < WHHT_SZ) {
        int hh = idx / (3 * HH);
        int c  = idx % (3 * HH);
        ws[WHHT_OFF + idx] = W_hh[c * HH + hh];
    }
}

// Kernel 1: Esum[b,j,:] = sum_i A[b,i,j] * relu(E[b,i,j,:] @ W_e + b_e)
// One block per (node, half): 256 threads, each owns 2 output cols.
// W_e slice (32 k x 2 cols) lives in registers; active edges via ballot on A column.
__global__ __launch_bounds__(256) void edge_mm_kernel(
    const float* __restrict__ A, const float* __restrict__ E,
    const float* __restrict__ W_e, const float* __restrict__ b_e,
    float* __restrict__ Esum) {
    const int half = blockIdx.x & 1;
    const int node = blockIdx.x >> 1;      // b*48 + j
    const int b = node / NA;
    const int j = node - b * NA;
    const int t = threadIdx.x;
    const int c0 = half * 512 + 2 * t;

    // Load this thread's W_e slice into registers (coalesced float2 per k-row).
    float w[2 * EIN];
    #pragma unroll
    for (int k = 0; k < EIN; ++k) {
        const float2 wv = *(const float2*)(W_e + k * (HG * HH) + c0);
        w[2 * k]     = wv.x;
        w[2 * k + 1] = wv.y;
    }
    const float be0 = b_e[c0];
    const float be1 = b_e[c0 + 1];

    // Active-edge bitmask from column j of A (A entries are exactly 0.0/1.0).
    const int lane = t & 63;
    float a = 0.0f;
    if (lane < NA) a = A[(size_t)(b * NA + lane) * NA + j];
    unsigned long long m = __ballot(a != 0.0f);

    float acc0 = 0.0f, acc1 = 0.0f;
    while (m) {
        const int i = __builtin_ctzll((long long)m);
        m &= m - 1;
        // Broadcast-load E row (128 B, all lanes same address -> 1 line/req).
        const float4* ep = (const float4*)(E + ((size_t)(b * NA + i) * NA + j) * EIN);
        float e[EIN];
        #pragma unroll
        for (int q = 0; q < EIN / 4; ++q) {
            const float4 ev = ep[q];
            e[4 * q]     = ev.x;
            e[4 * q + 1] = ev.y;
            e[4 * q + 2] = ev.z;
            e[4 * q + 3] = ev.w;
        }
        float v0 = be0, v1 = be1;
        #pragma unroll
        for (int k = 0; k < EIN; ++k) {
            v0 = fmaf(e[k], w[2 * k], v0);
            v1 = fmaf(e[k], w[2 * k + 1], v1);
        }
        // relu per-edge BEFORE the sum over i
        acc0 += fmaxf(v0, 0.0f);
        acc1 += fmaxf(v1, 0.0f);
    }
    float2* outp = (float2*)(Esum + (size_t)node * (HG * HH) + c0);
    *outp = make_float2(acc0, acc1);
}

// Kernel 2: per-node hv = relu(h@W_h+b_h)*maskh, then 5 GRUCell steps.
// One wave per node; hc[t] lives in lane t; cross-lane via shuffles.
__global__ __launch_bounds__(64) void gru_kernel(
    const float* __restrict__ A, const float* __restrict__ h,
    const float* __restrict__ W_h, const float* __restrict__ b_h,
    const float* __restrict__ b_ih, const float* __restrict__ b_hh,
    const float* __restrict__ ws, float* __restrict__ out) {
    const int node = blockIdx.x;           // b*48 + j
    const int lane = threadIdx.x;
    const float* Esum = ws + (size_t)node * (HG * HH);
    const float* WihT = ws + WIHT_OFF;
    const float* WhhT = ws + WHHT_OFF;

    // maskh: row-sum of A[b, j, :] > 0.1  <=>  any nonzero (entries are 0/1)
    float a = (lane < NA) ? A[(size_t)node * NA + lane] : 0.0f;
    const unsigned long long m = __ballot(a != 0.0f);
    const float maskh = (m != 0ull) ? 1.0f : 0.0f;

    // hv[t] = relu(b_h[t] + sum_k h[k] * W_h[k][t]) * maskh
    const float hr = h[(size_t)node * HH + lane];
    float acc = b_h[lane];
    #pragma unroll
    for (int k = 0; k < HIN; ++k) {
        const float hk = __shfl(hr, k);
        acc = fmaf(hk, W_h[k * HH + lane], acc);
    }
    float hc = fmaxf(acc, 0.0f) * maskh;

    for (int it = 0; it < NCELLS; ++it) {
        // M[g] = sum_h Esum[g*64 + h] * hc[h]  (butterfly sum -> all lanes)
        float M[HG];
        #pragma unroll
        for (int g = 0; g < HG; ++g) {
            float p = Esum[g * HH + lane] * hc;
            #pragma unroll
            for (int off = 32; off >= 1; off >>= 1)
                p += __shfl_xor(p, off);
            M[g] = p;
        }
        // gi = M @ W_ih.T + b_ih   (lane t computes rows t, 64+t, 128+t)
        float gr = b_ih[lane], gz = b_ih[HH + lane], gn = b_ih[2 * HH + lane];
        #pragma unroll
        for (int g = 0; g < HG; ++g) {
            const float* wp = WihT + g * (3 * HH);
            gr = fmaf(M[g], wp[lane], gr);
            gz = fmaf(M[g], wp[HH + lane], gz);
            gn = fmaf(M[g], wp[2 * HH + lane], gn);
        }
        // gh = hc @ W_hh.T + b_hh
        float hrr = b_hh[lane], hz = b_hh[HH + lane], hn = b_hh[2 * HH + lane];
        #pragma unroll
        for (int hx = 0; hx < HH; ++hx) {
            const float hv = __shfl(hc, hx);
            const float* wp = WhhT + hx * (3 * HH);
            hrr = fmaf(hv, wp[lane], hrr);
            hz  = fmaf(hv, wp[HH + lane], hz);
            hn  = fmaf(hv, wp[2 * HH + lane], hn);
        }
        const float r = 1.0f / (1.0f + __expf(-(gr + hrr)));
        const float z = 1.0f / (1.0f + __expf(-(gz + hz)));
        const float nin = gn + r * hn;
        const float n = 1.0f - 2.0f / (__expf(2.0f * nin) + 1.0f);  // tanh(nin)
        hc = (1.0f - z) * n + z * hc;
    }
    out[(size_t)node * HH + lane] = hc;
}

extern "C" void kernel_launch(void* const* d_in, const int* in_sizes, int n_in,
                              void* d_out, int out_size, void* d_ws, size_t ws_size,
                              hipStream_t stream) {
    const float* A    = (const float*)d_in[0];
    const float* h    = (const float*)d_in[1];
    const float* E    = (const float*)d_in[2];
    const float* W_h  = (const float*)d_in[3];
    const float* b_h  = (const float*)d_in[4];
    const float* W_e  = (const float*)d_in[5];
    const float* b_e  = (const float*)d_in[6];
    const float* W_ih = (const float*)d_in[7];
    const float* b_ih = (const float*)d_in[8];
    const float* W_hh = (const float*)d_in[9];
    const float* b_hh = (const float*)d_in[10];
    float* ws  = (float*)d_ws;
    float* out = (float*)d_out;

    hipLaunchKernelGGL(transpose_weights, dim3((WIHT_SZ + WHHT_SZ + 255) / 256),
                       dim3(256), 0, stream, W_ih, W_hh, ws);
    hipLaunchKernelGGL(edge_mm_kernel, dim3(NB * NA * 2), dim3(256), 0, stream,
                       A, E, W_e, b_e, ws);
    hipLaunchKernelGGL(gru_kernel, dim3(NB * NA), dim3(64), 0, stream,
                       A, h, W_h, b_h, b_ih, b_hh, ws, out);
}

// Round 2
// 154.923 us; speedup vs baseline: 1.0991x; 1.0991x over previous
//
#include <hip/hip_runtime.h>
#include <stdint.h>

#define NB 32
#define NA 48
#define HIN 64
#define EIN 32
#define HH 64
#define HG 16
#define NCELLS 5
#define GH (HG * HH)   // 1024

// One block per node (b,j). 512 threads.
// Phase 1 (all 512): Esum[b,j,:] = sum_i A[b,i,j]*relu(E[b,i,j,:]@W_e + b_e) -> LDS
// Phase 2 (192 threads): 5 GRUCell steps, gate weights cached in registers.
__global__ __launch_bounds__(512) void fused_kernel(
    const float* __restrict__ A,  const float* __restrict__ h,
    const float* __restrict__ E,
    const float* __restrict__ W_h, const float* __restrict__ b_h,
    const float* __restrict__ W_e, const float* __restrict__ b_e,
    const float* __restrict__ W_ih, const float* __restrict__ b_ih,
    const float* __restrict__ W_hh, const float* __restrict__ b_hh,
    float* __restrict__ out)
{
    __shared__ float Esum_s[GH];     // 4 KB
    __shared__ float hc_s[HH];
    __shared__ float M_s[HG];
    __shared__ float gsum_s[2 * HH]; // combined r,z pre-activations
    __shared__ float gin_s[HH];      // i_n
    __shared__ float ghn_s[HH];      // h_n

    const int node = blockIdx.x;        // b*48 + j
    const int b = node / NA;
    const int j = node - b * NA;
    const int tid  = threadIdx.x;
    const int lane = tid & 63;

    // ---------------- Phase 1: edge matmul into LDS ----------------
    const int c0 = 2 * tid;             // this thread's two output columns
    float w[2 * EIN];
    #pragma unroll
    for (int k = 0; k < EIN; ++k) {
        const float2 wv = *(const float2*)(W_e + k * GH + c0);
        w[2 * k]     = wv.x;
        w[2 * k + 1] = wv.y;
    }
    float acc0 = 0.0f, acc1 = 0.0f;
    {
        // active-edge bitmask from column j of A (entries are exactly 0/1);
        // each wave computes the same mask independently (L1-hot loads)
        float a = (lane < NA) ? A[(size_t)(b * NA + lane) * NA + j] : 0.0f;
        unsigned long long m = __ballot(a != 0.0f);
        const float be0 = b_e[c0], be1 = b_e[c0 + 1];
        while (m) {
            const int i = __builtin_ctzll(m);
            m &= m - 1;
            const float4* ep = (const float4*)(E + ((size_t)(b * NA + i) * NA + j) * EIN);
            float v0 = be0, v1 = be1;
            #pragma unroll
            for (int q = 0; q < EIN / 4; ++q) {
                const float4 ev = ep[q];   // broadcast load: all lanes same addr
                v0 = fmaf(ev.x, w[8 * q + 0], v0); v1 = fmaf(ev.x, w[8 * q + 1], v1);
                v0 = fmaf(ev.y, w[8 * q + 2], v0); v1 = fmaf(ev.y, w[8 * q + 3], v1);
                v0 = fmaf(ev.z, w[8 * q + 4], v0); v1 = fmaf(ev.z, w[8 * q + 5], v1);
                v0 = fmaf(ev.w, w[8 * q + 6], v0); v1 = fmaf(ev.w, w[8 * q + 7], v1);
            }
            acc0 += fmaxf(v0, 0.0f);   // relu per-edge BEFORE the i-sum
            acc1 += fmaxf(v1, 0.0f);
        }
    }
    *(float2*)(Esum_s + c0) = make_float2(acc0, acc1);
    __syncthreads();

    // ---------------- Phase 2 setup ----------------
    // Gate-weight registers for threads 0..191 (rows of W_ih / W_hh are
    // contiguous per thread -> float4 preload, one time, L1/L2-hot).
    float wih[HG], whh[HH];
    float bih_c = 0.0f, bhh_c = 0.0f;
    if (tid < 3 * HH) {
        #pragma unroll
        for (int g = 0; g < HG; g += 4) {
            const float4 v = *(const float4*)(W_ih + (size_t)tid * HG + g);
            wih[g] = v.x; wih[g + 1] = v.y; wih[g + 2] = v.z; wih[g + 3] = v.w;
        }
        #pragma unroll
        for (int k = 0; k < HH; k += 4) {
            const float4 v = *(const float4*)(W_hh + (size_t)tid * HH + k);
            whh[k] = v.x; whh[k + 1] = v.y; whh[k + 2] = v.z; whh[k + 3] = v.w;
        }
        bih_c = b_ih[tid];
        bhh_c = b_hh[tid];
    }

    // hv = relu(h @ W_h + b_h) * maskh  (wave 0 only; maskh from ROW j of A)
    if (tid < HH) {
        const float a = (lane < NA) ? A[(size_t)node * NA + lane] : 0.0f;
        const unsigned long long mrow = __ballot(a != 0.0f);
        const float maskh = (mrow != 0ull) ? 1.0f : 0.0f;
        const float hr = h[(size_t)node * HIN + lane];
        float acc = b_h[lane];
        #pragma unroll
        for (int k = 0; k < HIN; ++k)
            acc = fmaf(__shfl(hr, k), W_h[k * HH + lane], acc);
        hc_s[lane] = fmaxf(acc, 0.0f) * maskh;
    }
    __syncthreads();

    // ---------------- Phase 2: 5 GRUCell iterations ----------------
    for (int it = 0; it < NCELLS; ++it) {
        // M[g] = dot(Esum[g,:], hc) : lanes 4g..4g+3 each sum 16 elems
        if (tid < HH) {
            const int g = tid >> 2, q = tid & 3;
            const float* es = Esum_s + g * HH + q * 16;
            const float* hp = hc_s + q * 16;
            float p = 0.0f;
            #pragma unroll
            for (int k = 0; k < 16; ++k) p = fmaf(es[k], hp[k], p);
            p += __shfl_xor(p, 1);
            p += __shfl_xor(p, 2);
            if (q == 0) M_s[g] = p;
        }
        __syncthreads();
        // thread c: gi[c] = b_ih[c] + M . W_ih[c,:], gh[c] = b_hh[c] + hc . W_hh[c,:]
        if (tid < 3 * HH) {
            float gi = bih_c, gh = bhh_c;
            #pragma unroll
            for (int g = 0; g < HG; ++g) gi = fmaf(M_s[g], wih[g], gi);
            #pragma unroll
            for (int k = 0; k < HH; ++k) gh = fmaf(hc_s[k], whh[k], gh);
            if (tid < 2 * HH) gsum_s[tid] = gi + gh;         // r,z: only need sum
            else { gin_s[tid - 2 * HH] = gi; ghn_s[tid - 2 * HH] = gh; }
        }
        __syncthreads();
        if (tid < HH) {
            const float r = 1.0f / (1.0f + __expf(-gsum_s[tid]));
            const float z = 1.0f / (1.0f + __expf(-gsum_s[HH + tid]));
            const float nin = gin_s[tid] + r * ghn_s[tid];
            const float n = 1.0f - 2.0f / (__expf(2.0f * nin) + 1.0f);  // tanh
            hc_s[tid] = (1.0f - z) * n + z * hc_s[tid];
        }
        __syncthreads();
    }

    if (tid < HH) out[(size_t)node * HH + tid] = hc_s[tid];
}

extern "C" void kernel_launch(void* const* d_in, const int* in_sizes, int n_in,
                              void* d_out, int out_size, void* d_ws, size_t ws_size,
                              hipStream_t stream) {
    const float* A    = (const float*)d_in[0];
    const float* h    = (const float*)d_in[1];
    const float* E    = (const float*)d_in[2];
    const float* W_h  = (const float*)d_in[3];
    const float* b_h  = (const float*)d_in[4];
    const float* W_e  = (const float*)d_in[5];
    const float* b_e  = (const float*)d_in[6];
    const float* W_ih = (const float*)d_in[7];
    const float* b_ih = (const float*)d_in[8];
    const float* W_hh = (const float*)d_in[9];
    const float* b_hh = (const float*)d_in[10];
    float* out = (float*)d_out;

    hipLaunchKernelGGL(fused_kernel, dim3(NB * NA), dim3(512), 0, stream,
                       A, h, E, W_h, b_h, W_e, b_e, W_ih, b_ih, W_hh, b_hh, out);
}